// Round 1
// baseline (237.218 us; speedup 1.0000x reference)
//
#include <hip/hip_runtime.h>

#define DIM 512
#define WAVE 64
#define WAVES_PER_BLOCK 4
#define BLOCK (WAVE * WAVES_PER_BLOCK)

// One wave (64 lanes) per row; 8 elements/lane held in registers.
// Michelot's algorithm for exact simplex-projection threshold:
//   tau_{t+1} = (sum_{z_i > tau_t} z_i - 1) / #{z_i > tau_t}
// Support sets are nested & shrinking; stop when the count stabilizes
// (equal count <=> equal set <=> fixed point). Exact, no sort needed.
__global__ __launch_bounds__(BLOCK) void sparsemax_kernel(
    const float* __restrict__ x, float* __restrict__ out, int batch) {
    const int row  = blockIdx.x * WAVES_PER_BLOCK + (threadIdx.x >> 6);
    const int lane = threadIdx.x & 63;
    if (row >= batch) return;

    const float4* xr = reinterpret_cast<const float4*>(x) + (size_t)row * (DIM / 4);
    float4 a = xr[lane];
    float4 b = xr[lane + WAVE];
    float z[8] = {a.x, a.y, a.z, a.w, b.x, b.y, b.z, b.w};

    // --- mean-center (matches reference numerics; shift-invariant anyway) ---
    float s = 0.f;
#pragma unroll
    for (int j = 0; j < 8; ++j) s += z[j];
#pragma unroll
    for (int off = 32; off >= 1; off >>= 1) s += __shfl_xor(s, off, 64);
    const float mean = s * (1.0f / (float)DIM);
#pragma unroll
    for (int j = 0; j < 8; ++j) z[j] -= mean;

    // --- Michelot iteration (first pass with tau=-inf == init over full set) ---
    float tau   = -3.4e38f;
    float kprev = -1.0f;
    for (int it = 0; it < 64; ++it) {
        float S = 0.f, K = 0.f;
#pragma unroll
        for (int j = 0; j < 8; ++j) {
            const bool in = z[j] > tau;
            S += in ? z[j] : 0.f;
            K += in ? 1.0f : 0.f;
        }
#pragma unroll
        for (int off = 32; off >= 1; off >>= 1) {
            S += __shfl_xor(S, off, 64);
            K += __shfl_xor(K, off, 64);
        }
        const float ntau = (S - 1.0f) / K;   // K >= 1 always (max elem in support)
        if (K == kprev) break;               // set stable -> ntau == tau already
        kprev = K;
        tau   = ntau;
    }

    // --- epilogue: out = max(0, z - tau), vectorized store ---
    float4 oa, ob;
    oa.x = fmaxf(0.f, z[0] - tau);
    oa.y = fmaxf(0.f, z[1] - tau);
    oa.z = fmaxf(0.f, z[2] - tau);
    oa.w = fmaxf(0.f, z[3] - tau);
    ob.x = fmaxf(0.f, z[4] - tau);
    ob.y = fmaxf(0.f, z[5] - tau);
    ob.z = fmaxf(0.f, z[6] - tau);
    ob.w = fmaxf(0.f, z[7] - tau);
    float4* orow = reinterpret_cast<float4*>(out) + (size_t)row * (DIM / 4);
    orow[lane]        = oa;
    orow[lane + WAVE] = ob;
}

extern "C" void kernel_launch(void* const* d_in, const int* in_sizes, int n_in,
                              void* d_out, int out_size, void* d_ws, size_t ws_size,
                              hipStream_t stream) {
    const float* x = (const float*)d_in[0];
    float* out     = (float*)d_out;
    const int batch = in_sizes[0] / DIM;  // 65536
    const int grid  = (batch + WAVES_PER_BLOCK - 1) / WAVES_PER_BLOCK;
    sparsemax_kernel<<<grid, BLOCK, 0, stream>>>(x, out, batch);
}

// Round 2
// 226.448 us; speedup vs baseline: 1.0476x; 1.0476x over previous
//
#include <hip/hip_runtime.h>

#define DIM 512
#define WAVE 64
#define WPB 4
#define BLOCK (WAVE * WPB)

// xor-butterfly allreduce: 5 ds_swizzle stages (xor 1..16, static imm, no addr
// VALU) + 1 ds_bpermute for the cross-32 stage (addr precomputed once).
// Result is bitwise-identical in all 64 lanes.
__device__ __forceinline__ float bfly_sum(float x, int bp_addr) {
    x += __int_as_float(__builtin_amdgcn_ds_swizzle(__float_as_int(x), (1  << 10) | 0x1f));
    x += __int_as_float(__builtin_amdgcn_ds_swizzle(__float_as_int(x), (2  << 10) | 0x1f));
    x += __int_as_float(__builtin_amdgcn_ds_swizzle(__float_as_int(x), (4  << 10) | 0x1f));
    x += __int_as_float(__builtin_amdgcn_ds_swizzle(__float_as_int(x), (8  << 10) | 0x1f));
    x += __int_as_float(__builtin_amdgcn_ds_swizzle(__float_as_int(x), (16 << 10) | 0x1f));
    x += __int_as_float(__builtin_amdgcn_ds_bpermute(bp_addr, __float_as_int(x)));
    return x;
}

__device__ __forceinline__ float bfly_max(float x, int bp_addr) {
    x = fmaxf(x, __int_as_float(__builtin_amdgcn_ds_swizzle(__float_as_int(x), (1  << 10) | 0x1f)));
    x = fmaxf(x, __int_as_float(__builtin_amdgcn_ds_swizzle(__float_as_int(x), (2  << 10) | 0x1f)));
    x = fmaxf(x, __int_as_float(__builtin_amdgcn_ds_swizzle(__float_as_int(x), (4  << 10) | 0x1f)));
    x = fmaxf(x, __int_as_float(__builtin_amdgcn_ds_swizzle(__float_as_int(x), (8  << 10) | 0x1f)));
    x = fmaxf(x, __int_as_float(__builtin_amdgcn_ds_swizzle(__float_as_int(x), (16 << 10) | 0x1f)));
    x = fmaxf(x, __int_as_float(__builtin_amdgcn_ds_bpermute(bp_addr, __float_as_int(x))));
    return x;
}

__global__ __launch_bounds__(BLOCK) void sparsemax_kernel(
    const float* __restrict__ x, float* __restrict__ out, int batch) {
    const int row  = blockIdx.x * WPB + (threadIdx.x >> 6);
    const int lane = threadIdx.x & 63;
    if (row >= batch) return;

    const int bp_addr = (lane ^ 32) << 2;  // ds_bpermute byte addr, hoisted

    const float4* xr = reinterpret_cast<const float4*>(x) + (size_t)row * (DIM / 4);
    float4 a = xr[lane];
    float4 b = xr[lane + WAVE];
    float z[8] = {a.x, a.y, a.z, a.w, b.x, b.y, b.z, b.w};

    // --- start from tau0 = max - 1 (valid lower bound: p_max <= 1) ---
    float m = fmaxf(fmaxf(fmaxf(z[0], z[1]), fmaxf(z[2], z[3])),
                    fmaxf(fmaxf(z[4], z[5]), fmaxf(z[6], z[7])));
    m = bfly_max(m, bp_addr);
    float tau = m - 1.0f;

    // --- Michelot / Newton: tau' = (S-1)/K over {z > tau}; sets nested &
    //     shrinking, tau monotone up, exact finite convergence (K stable
    //     <=> set stable <=> fixed point). K via scalar-pipe ballots. ---
    int kprev = 0;
    for (int it = 0; it < 32; ++it) {
        float S = 0.f;
        int   K = 0;
#pragma unroll
        for (int j = 0; j < 8; ++j) {
            const bool in = z[j] > tau;
            S += in ? z[j] : 0.f;
            K += (int)__popcll(__ballot(in));
        }
        S = bfly_sum(S, bp_addr);
        if (K == kprev) break;   // set unchanged -> tau is the fixed point
        kprev = K;
        tau = (S - 1.0f) * __builtin_amdgcn_rcpf((float)K);  // K >= 1 (max in set)
    }

    // --- epilogue: out = max(0, z - tau) ---
    float4 oa, ob;
    oa.x = fmaxf(0.f, z[0] - tau);
    oa.y = fmaxf(0.f, z[1] - tau);
    oa.z = fmaxf(0.f, z[2] - tau);
    oa.w = fmaxf(0.f, z[3] - tau);
    ob.x = fmaxf(0.f, z[4] - tau);
    ob.y = fmaxf(0.f, z[5] - tau);
    ob.z = fmaxf(0.f, z[6] - tau);
    ob.w = fmaxf(0.f, z[7] - tau);
    float4* orow = reinterpret_cast<float4*>(out) + (size_t)row * (DIM / 4);
    orow[lane]        = oa;
    orow[lane + WAVE] = ob;
}

extern "C" void kernel_launch(void* const* d_in, const int* in_sizes, int n_in,
                              void* d_out, int out_size, void* d_ws, size_t ws_size,
                              hipStream_t stream) {
    const float* x = (const float*)d_in[0];
    float* out     = (float*)d_out;
    const int batch = in_sizes[0] / DIM;  // 65536
    const int grid  = (batch + WPB - 1) / WPB;
    sparsemax_kernel<<<grid, BLOCK, 0, stream>>>(x, out, batch);
}